// Round 3
// baseline (243.474 us; speedup 1.0000x reference)
//
#include <hip/hip_runtime.h>

// TriPlane sampler, MI355X — round 3.
// images: (N=4, 3, C=32, 256, 256) f32; points: (M, 3) f32; out: (N,3,M,C) f32
//
// Pass 1: interleave img (n,p,c,y,x) f32 -> ws (p, y, x, n, c) bf16 (one
//         pixel = 256 B serving all 4 images' 32 channels).
// Pass 2: per-plane counting sort of point indices by 8x8-px cell
//         (hist -> scan -> scatter) so gathers are spatially coherent.
// Pass 3: sample in sorted order: corners become L2/L3 hits; out writes are
//         scattered but aligned 128 B chunks (full lines).

#define NBINS 1024  // 32x32 cells of 8x8 px

__device__ __forceinline__ float bf2f(unsigned int u) {
  union { unsigned int i; float f; } x; x.i = u << 16; return x.f;
}
__device__ __forceinline__ unsigned short f2bf(float f) {
  union { float f; unsigned int i; } x; x.f = f;
  unsigned int b = x.i + 0x7FFFu + ((x.i >> 16) & 1u);
  return (unsigned short)(b >> 16);
}

// grid (4 wtiles, 256 y, 3 p), 256 threads. N=4 specialized.
__global__ __launch_bounds__(256) void interleave_kernel(
    const float* __restrict__ img, unsigned short* __restrict__ ws) {
  __shared__ float tile[4 * 2145];  // idx = n*2145 + c*67 + w
  int wt = blockIdx.x, y = blockIdx.y, p = blockIdx.z;
  int t = threadIdx.x;
  int w0 = wt * 64;
  int wi = t & 63, wq = t >> 6;
  const float* src = img + (size_t)p * (32 * 65536) + (size_t)y * 256 + w0 + wi;
#pragma unroll
  for (int k = 0; k < 32; ++k) {
    int rr = k * 4 + wq;  // 0..127 = n*32+c
    int n = rr >> 5, c = rr & 31;
    tile[n * 2145 + c * 67 + wi] =
        src[(size_t)n * (3 * 32 * 65536) + (size_t)c * 65536];
  }
  __syncthreads();
  int j = t & 3, n = (t >> 2) & 3, wb = t >> 4;
  uint4* dst = (uint4*)ws;
#pragma unroll
  for (int k = 0; k < 4; ++k) {
    int w = wb + k * 16;
    unsigned int pk[4];
#pragma unroll
    for (int h = 0; h < 4; ++h) {
      int c = j * 8 + h * 2;
      unsigned int lo = f2bf(tile[n * 2145 + c * 67 + w]);
      unsigned int hi = f2bf(tile[n * 2145 + (c + 1) * 67 + w]);
      pk[h] = lo | (hi << 16);
    }
    size_t pix = (size_t)p * 65536 + (size_t)y * 256 + w0 + w;
    dst[pix * 16 + n * 4 + j] = make_uint4(pk[0], pk[1], pk[2], pk[3]);
  }
}

__device__ __forceinline__ void plane_xy(
    const float* __restrict__ pts, int p, int m, float& x, float& y) {
  float px = pts[m * 3 + 0];
  float py = pts[m * 3 + 1];
  float pz = pts[m * 3 + 2];
  // plane0=(x,y) plane1=(x,z) plane2=(z,x); scale 2/1.6 = 1.25
  float gx = (p == 2) ? pz : px;
  float gy = (p == 0) ? py : ((p == 1) ? pz : px);
  x = fmaf(gx, 160.0f, 127.5f);
  y = fmaf(gy, 160.0f, 127.5f);
}

__device__ __forceinline__ int cell_bin(float x, float y) {
  int ix = min(max((int)floorf(x), 0), 255);
  int iy = min(max((int)floorf(y), 0), 255);
  return (iy >> 3) * 32 + (ix >> 3);
}

__global__ __launch_bounds__(256) void zero_hist_kernel(int* __restrict__ hist) {
  int t = blockIdx.x * 256 + threadIdx.x;
  if (t < 3 * NBINS) hist[t] = 0;
}

__global__ __launch_bounds__(256) void hist_kernel(
    const float* __restrict__ pts, int* __restrict__ hist, int M) {
  int p = blockIdx.y;
  int m = blockIdx.x * 256 + threadIdx.x;
  if (m >= M) return;
  float x, y;
  plane_xy(pts, p, m, x, y);
  atomicAdd(&hist[p * NBINS + cell_bin(x, y)], 1);
}

// one block, 1024 threads; exclusive scan per plane -> cursor
__global__ __launch_bounds__(1024) void scan_kernel(
    const int* __restrict__ hist, int* __restrict__ cursor) {
  __shared__ int sm[NBINS];
  int t = threadIdx.x;
  for (int p = 0; p < 3; ++p) {
    int v = hist[p * NBINS + t];
    sm[t] = v;
    __syncthreads();
    for (int o = 1; o < NBINS; o <<= 1) {
      int x = sm[t];
      if (t >= o) x += sm[t - o];
      __syncthreads();
      sm[t] = x;
      __syncthreads();
    }
    cursor[p * NBINS + t] = sm[t] - v;  // exclusive
    __syncthreads();
  }
}

__global__ __launch_bounds__(256) void scatter_kernel(
    const float* __restrict__ pts, int* __restrict__ cursor,
    int* __restrict__ sorted, int M) {
  int p = blockIdx.y;
  int m = blockIdx.x * 256 + threadIdx.x;
  if (m >= M) return;
  float x, y;
  plane_xy(pts, p, m, x, y);
  int pos = atomicAdd(&cursor[p * NBINS + cell_bin(x, y)], 1);
  sorted[p * M + pos] = m;
}

// 8 lanes per (plane, point); ws is (p, pix, n, c) bf16, N=4.
__global__ __launch_bounds__(256) void sample_bf16_kernel(
    const float* __restrict__ pts, const unsigned short* __restrict__ ws,
    const int* __restrict__ sorted, float* __restrict__ out, int M) {
  int p = blockIdx.y;
  int tid = blockIdx.x * 256 + threadIdx.x;
  int c4 = tid & 7, idx = tid >> 3;
  if (idx >= M) return;
  int m = sorted[p * M + idx];
  float x, y;
  plane_xy(pts, p, m, x, y);
  float x0f = floorf(x), y0f = floorf(y);
  int ix0 = (int)x0f, iy0 = (int)y0f;
  int ix1 = ix0 + 1, iy1 = iy0 + 1;
  float wx1 = x - x0f, wx0 = 1.0f - wx1;
  float wy1 = y - y0f, wy0 = 1.0f - wy1;
  bool vx0 = (unsigned)ix0 < 256u, vx1 = (unsigned)ix1 < 256u;
  bool vy0 = (unsigned)iy0 < 256u, vy1 = (unsigned)iy1 < 256u;
  float w00 = (vx0 && vy0) ? wx0 * wy0 : 0.0f;
  float w01 = (vx1 && vy0) ? wx1 * wy0 : 0.0f;
  float w10 = (vx0 && vy1) ? wx0 * wy1 : 0.0f;
  float w11 = (vx1 && vy1) ? wx1 * wy1 : 0.0f;
  int xc0 = min(max(ix0, 0), 255), xc1 = min(max(ix1, 0), 255);
  int yc0 = min(max(iy0, 0), 255), yc1 = min(max(iy1, 0), 255);
  size_t q00 = ((size_t)yc0 * 256 + xc0) * 128;
  size_t q01 = ((size_t)yc0 * 256 + xc1) * 128;
  size_t q10 = ((size_t)yc1 * 256 + xc0) * 128;
  size_t q11 = ((size_t)yc1 * 256 + xc1) * 128;
  const unsigned short* base = ws + (size_t)p * 65536 * 128 + c4 * 4;
#pragma unroll
  for (int n = 0; n < 4; ++n) {
    int no = n * 32;
    ushort4 v00 = *(const ushort4*)(base + q00 + no);
    ushort4 v01 = *(const ushort4*)(base + q01 + no);
    ushort4 v10 = *(const ushort4*)(base + q10 + no);
    ushort4 v11 = *(const ushort4*)(base + q11 + no);
    float4 r;
    r.x = w00 * bf2f(v00.x) + w01 * bf2f(v01.x) + w10 * bf2f(v10.x) + w11 * bf2f(v11.x);
    r.y = w00 * bf2f(v00.y) + w01 * bf2f(v01.y) + w10 * bf2f(v10.y) + w11 * bf2f(v11.y);
    r.z = w00 * bf2f(v00.z) + w01 * bf2f(v01.z) + w10 * bf2f(v10.z) + w11 * bf2f(v11.z);
    r.w = w00 * bf2f(v00.w) + w01 * bf2f(v01.w) + w10 * bf2f(v10.w) + w11 * bf2f(v11.w);
    *(float4*)(out + ((size_t)(n * 3 + p) * M + m) * 32 + c4 * 4) = r;
  }
}

// Generic fallback (any N, no workspace): sample directly from (B,C,H,W).
__global__ __launch_bounds__(256) void sample_direct(
    const float* __restrict__ pts, const float* __restrict__ img,
    float* __restrict__ out, int M, int N) {
  int p = blockIdx.y;
  int tid = blockIdx.x * 256 + threadIdx.x;
  int c4 = tid & 7;
  int m = tid >> 3;
  if (m >= M) return;
  float x, y;
  plane_xy(pts, p, m, x, y);
  float x0f = floorf(x), y0f = floorf(y);
  int ix0 = (int)x0f, iy0 = (int)y0f;
  int ix1 = ix0 + 1, iy1 = iy0 + 1;
  float wx1 = x - x0f, wx0 = 1.0f - wx1;
  float wy1 = y - y0f, wy0 = 1.0f - wy1;
  bool vx0 = (unsigned)ix0 < 256u, vx1 = (unsigned)ix1 < 256u;
  bool vy0 = (unsigned)iy0 < 256u, vy1 = (unsigned)iy1 < 256u;
  float w00 = (vx0 && vy0) ? wx0 * wy0 : 0.0f;
  float w01 = (vx1 && vy0) ? wx1 * wy0 : 0.0f;
  float w10 = (vx0 && vy1) ? wx0 * wy1 : 0.0f;
  float w11 = (vx1 && vy1) ? wx1 * wy1 : 0.0f;
  int p00 = (min(max(iy0, 0), 255)) * 256 + (min(max(ix0, 0), 255));
  int p01 = (min(max(iy0, 0), 255)) * 256 + (min(max(ix1, 0), 255));
  int p10 = (min(max(iy1, 0), 255)) * 256 + (min(max(ix0, 0), 255));
  int p11 = (min(max(iy1, 0), 255)) * 256 + (min(max(ix1, 0), 255));
  for (int n = 0; n < N; ++n) {
    const float* base = img + (size_t)(n * 3 + p) * 32 * 65536;
    float4 r;
    float* rr = &r.x;
#pragma unroll
    for (int j = 0; j < 4; ++j) {
      const float* pl = base + (size_t)(c4 * 4 + j) * 65536;
      rr[j] = w00 * pl[p00] + w01 * pl[p01] + w10 * pl[p10] + w11 * pl[p11];
    }
    *(float4*)(out + ((size_t)(n * 3 + p) * M + m) * 32 + c4 * 4) = r;
  }
}

extern "C" void kernel_launch(void* const* d_in, const int* in_sizes, int n_in,
                              void* d_out, int out_size, void* d_ws, size_t ws_size,
                              hipStream_t stream) {
  const float* pts = (const float*)d_in[0];
  const float* img = (const float*)d_in[1];
  float* out = (float*)d_out;
  int M = in_sizes[0] / 3;
  int N = in_sizes[1] / (3 * 32 * 256 * 256);
  int sblocks = (M * 8 + 255) / 256;
  dim3 sgrid(sblocks, 3);
  // ws layout
  size_t ws_bf16 = (size_t)3 * 65536 * 256;               // 50.3 MB
  size_t off_hist = ws_bf16;                               // 3*NBINS ints
  size_t off_cur  = off_hist + 3 * NBINS * sizeof(int);
  size_t off_sort = off_cur + 3 * NBINS * sizeof(int);
  size_t need = off_sort + (size_t)3 * M * sizeof(int);
  if (N == 4 && ws_size >= need) {
    unsigned short* wsb = (unsigned short*)d_ws;
    int* hist = (int*)((char*)d_ws + off_hist);
    int* cur  = (int*)((char*)d_ws + off_cur);
    int* sorted = (int*)((char*)d_ws + off_sort);
    int mb = (M + 255) / 256;
    interleave_kernel<<<dim3(4, 256, 3), 256, 0, stream>>>(img, wsb);
    zero_hist_kernel<<<(3 * NBINS + 255) / 256, 256, 0, stream>>>(hist);
    hist_kernel<<<dim3(mb, 3), 256, 0, stream>>>(pts, hist, M);
    scan_kernel<<<1, 1024, 0, stream>>>(hist, cur);
    scatter_kernel<<<dim3(mb, 3), 256, 0, stream>>>(pts, cur, sorted, M);
    sample_bf16_kernel<<<sgrid, 256, 0, stream>>>(pts, wsb, sorted, out, M);
  } else {
    sample_direct<<<sgrid, 256, 0, stream>>>(pts, img, out, M, N);
  }
}

// Round 5
// 105.291 us; speedup vs baseline: 2.3124x; 2.3124x over previous
//
#include <hip/hip_runtime.h>

// TriPlane sampler, MI355X — round 5 (r4 fixed: nontemporal builtins need
// clang ext_vector types, not HIP_vector_type).
// images: (N=4, 3, C=32, 256, 256) f32; points: (M, 3) f32; out: (N,3,M,C) f32
//
// Pass 1: interleave img (n,p,c,y,x) f32 -> ws (p, y, x, n, c) bf16.
//   One pixel block = 4n*32c bf16 = 256 B: one bilinear corner serves all 4
//   images from one contiguous burst. float4 + nontemporal loads (read-once).
// Pass 2: sample. 16 lanes per (plane, point); lane = (n, c8) owns 8 channels
//   of one image: 4 independent 16 B corner loads per thread, f32 accumulate,
//   nontemporal float4 stores (don't evict ws from L2/L3).

typedef float  f32x4 __attribute__((ext_vector_type(4)));
typedef unsigned int u32x4 __attribute__((ext_vector_type(4)));

__device__ __forceinline__ unsigned short f2bf(float f) {
  union { float f; unsigned int i; } x; x.f = f;
  unsigned int b = x.i + 0x7FFFu + ((x.i >> 16) & 1u);
  return (unsigned short)(b >> 16);
}

// grid (4 wtiles, 256 y, 3 p), 256 threads. N=4 specialized.
__global__ __launch_bounds__(256) void interleave_kernel(
    const float* __restrict__ img, unsigned short* __restrict__ ws) {
  __shared__ float tile[4 * 2145];  // idx = n*2145 + c*67 + w
  int wt = blockIdx.x, y = blockIdx.y, p = blockIdx.z;
  int t = threadIdx.x;
  int w0 = wt * 64;
  int fj = t & 15, rq = t >> 4;  // 16 float4-lanes per row, 16 rows per pass
  const float* srcbase = img + (size_t)p * (32 * 65536) + (size_t)y * 256 + w0;
#pragma unroll
  for (int k = 0; k < 8; ++k) {
    int rr = k * 16 + rq;        // 0..127 = n*32 + c
    int n = rr >> 5, c = rr & 31;
    f32x4 v = __builtin_nontemporal_load(
        (const f32x4*)(srcbase + (size_t)(n * 96 + c) * 65536) + fj);
    int idx = n * 2145 + c * 67 + fj * 4;
    tile[idx] = v.x; tile[idx + 1] = v.y; tile[idx + 2] = v.z; tile[idx + 3] = v.w;
  }
  __syncthreads();
  // write: pixel block = n*32+c (128 ushorts = 256B = 16 u32x4), coalesced
  int j = t & 3, n = (t >> 2) & 3, wb = t >> 4;
  u32x4* dst = (u32x4*)ws;
#pragma unroll
  for (int k = 0; k < 4; ++k) {
    int w = wb + k * 16;
    u32x4 pk;
#pragma unroll
    for (int h = 0; h < 4; ++h) {
      int c = j * 8 + h * 2;
      unsigned int lo = f2bf(tile[n * 2145 + c * 67 + w]);
      unsigned int hi = f2bf(tile[n * 2145 + (c + 1) * 67 + w]);
      pk[h] = lo | (hi << 16);
    }
    size_t pix = (size_t)p * 65536 + (size_t)y * 256 + w0 + w;
    dst[pix * 16 + n * 4 + j] = pk;
  }
}

__device__ __forceinline__ void plane_xy(
    const float* __restrict__ pts, int p, int m, float& x, float& y) {
  float px = pts[m * 3 + 0];
  float py = pts[m * 3 + 1];
  float pz = pts[m * 3 + 2];
  // plane0=(x,y) plane1=(x,z) plane2=(z,x); scale 2/1.6 = 1.25
  float gx = (p == 2) ? pz : px;
  float gy = (p == 0) ? py : ((p == 1) ? pz : px);
  x = fmaf(gx, 160.0f, 127.5f);
  y = fmaf(gy, 160.0f, 127.5f);
}

__device__ __forceinline__ void acc8(float w, u32x4 v, float* r) {
  union { unsigned int i; float f; } a, b;
#pragma unroll
  for (int k = 0; k < 4; ++k) {
    unsigned int u = v[k];
    a.i = u << 16;          // low bf16
    b.i = u & 0xFFFF0000u;  // high bf16
    r[2 * k]     = fmaf(w, a.f, r[2 * k]);
    r[2 * k + 1] = fmaf(w, b.f, r[2 * k + 1]);
  }
}

// 16 lanes per (plane, point); lane = (n = l>>2, c8 = l&3). ws (p,pix,n,c) bf16.
__global__ __launch_bounds__(256) void sample_bf16_kernel(
    const float* __restrict__ pts, const unsigned short* __restrict__ ws,
    float* __restrict__ out, int M) {
  int p = blockIdx.y;
  int tid = blockIdx.x * 256 + threadIdx.x;
  int m = tid >> 4;
  if (m >= M) return;
  int lane = tid & 15;
  int n = lane >> 2, c8 = lane & 3;
  float x, y;
  plane_xy(pts, p, m, x, y);
  float x0f = floorf(x), y0f = floorf(y);
  int ix0 = (int)x0f, iy0 = (int)y0f;
  int ix1 = ix0 + 1, iy1 = iy0 + 1;
  float wx1 = x - x0f, wx0 = 1.0f - wx1;
  float wy1 = y - y0f, wy0 = 1.0f - wy1;
  bool vx0 = (unsigned)ix0 < 256u, vx1 = (unsigned)ix1 < 256u;
  bool vy0 = (unsigned)iy0 < 256u, vy1 = (unsigned)iy1 < 256u;
  float w00 = (vx0 && vy0) ? wx0 * wy0 : 0.0f;
  float w01 = (vx1 && vy0) ? wx1 * wy0 : 0.0f;
  float w10 = (vx0 && vy1) ? wx0 * wy1 : 0.0f;
  float w11 = (vx1 && vy1) ? wx1 * wy1 : 0.0f;
  int xc0 = min(max(ix0, 0), 255), xc1 = min(max(ix1, 0), 255);
  int yc0 = min(max(iy0, 0), 255), yc1 = min(max(iy1, 0), 255);
  const unsigned short* base =
      ws + (size_t)p * (65536 * 128) + n * 32 + c8 * 8;
  u32x4 v00 = *(const u32x4*)(base + ((size_t)(yc0 * 256 + xc0) << 7));
  u32x4 v01 = *(const u32x4*)(base + ((size_t)(yc0 * 256 + xc1) << 7));
  u32x4 v10 = *(const u32x4*)(base + ((size_t)(yc1 * 256 + xc0) << 7));
  u32x4 v11 = *(const u32x4*)(base + ((size_t)(yc1 * 256 + xc1) << 7));
  float r[8] = {0, 0, 0, 0, 0, 0, 0, 0};
  acc8(w00, v00, r);
  acc8(w01, v01, r);
  acc8(w10, v10, r);
  acc8(w11, v11, r);
  float* op = out + ((size_t)(n * 3 + p) * M + m) * 32 + c8 * 8;
  f32x4 r0 = {r[0], r[1], r[2], r[3]};
  f32x4 r1 = {r[4], r[5], r[6], r[7]};
  __builtin_nontemporal_store(r0, (f32x4*)op);
  __builtin_nontemporal_store(r1, (f32x4*)(op + 4));
}

// Generic fallback (any N, no workspace): sample directly from (B,C,H,W).
__global__ __launch_bounds__(256) void sample_direct(
    const float* __restrict__ pts, const float* __restrict__ img,
    float* __restrict__ out, int M, int N) {
  int p = blockIdx.y;
  int tid = blockIdx.x * 256 + threadIdx.x;
  int c4 = tid & 7;
  int m = tid >> 3;
  if (m >= M) return;
  float x, y;
  plane_xy(pts, p, m, x, y);
  float x0f = floorf(x), y0f = floorf(y);
  int ix0 = (int)x0f, iy0 = (int)y0f;
  int ix1 = ix0 + 1, iy1 = iy0 + 1;
  float wx1 = x - x0f, wx0 = 1.0f - wx1;
  float wy1 = y - y0f, wy0 = 1.0f - wy1;
  bool vx0 = (unsigned)ix0 < 256u, vx1 = (unsigned)ix1 < 256u;
  bool vy0 = (unsigned)iy0 < 256u, vy1 = (unsigned)iy1 < 256u;
  float w00 = (vx0 && vy0) ? wx0 * wy0 : 0.0f;
  float w01 = (vx1 && vy0) ? wx1 * wy0 : 0.0f;
  float w10 = (vx0 && vy1) ? wx0 * wy1 : 0.0f;
  float w11 = (vx1 && vy1) ? wx1 * wy1 : 0.0f;
  int p00 = (min(max(iy0, 0), 255)) * 256 + (min(max(ix0, 0), 255));
  int p01 = (min(max(iy0, 0), 255)) * 256 + (min(max(ix1, 0), 255));
  int p10 = (min(max(iy1, 0), 255)) * 256 + (min(max(ix0, 0), 255));
  int p11 = (min(max(iy1, 0), 255)) * 256 + (min(max(ix1, 0), 255));
  for (int n = 0; n < N; ++n) {
    const float* base = img + (size_t)(n * 3 + p) * 32 * 65536;
    float4 r;
    float* rr = &r.x;
#pragma unroll
    for (int j = 0; j < 4; ++j) {
      const float* pl = base + (size_t)(c4 * 4 + j) * 65536;
      rr[j] = w00 * pl[p00] + w01 * pl[p01] + w10 * pl[p10] + w11 * pl[p11];
    }
    *(float4*)(out + ((size_t)(n * 3 + p) * M + m) * 32 + c4 * 4) = r;
  }
}

extern "C" void kernel_launch(void* const* d_in, const int* in_sizes, int n_in,
                              void* d_out, int out_size, void* d_ws, size_t ws_size,
                              hipStream_t stream) {
  const float* pts = (const float*)d_in[0];
  const float* img = (const float*)d_in[1];
  float* out = (float*)d_out;
  int M = in_sizes[0] / 3;
  int N = in_sizes[1] / (3 * 32 * 256 * 256);
  size_t need = (size_t)3 * 65536 * 256;  // 3 planes * 65536 px * 256 B
  if (N == 4 && ws_size >= need) {
    interleave_kernel<<<dim3(4, 256, 3), 256, 0, stream>>>(
        img, (unsigned short*)d_ws);
    int sblocks = (M * 16 + 255) / 256;
    sample_bf16_kernel<<<dim3(sblocks, 3), 256, 0, stream>>>(
        pts, (const unsigned short*)d_ws, out, M);
  } else {
    int sblocks = (M * 8 + 255) / 256;
    sample_direct<<<dim3(sblocks, 3), 256, 0, stream>>>(pts, img, out, M, N);
  }
}